// Round 8
// baseline (1242.016 us; speedup 1.0000x reference)
//
#include <hip/hip_runtime.h>

// SPModel_6846177870356: y = x@W^T + all2all permute. M=28160, N=K=2048.
// Inputs FP32 (harness-upcast fp16), output FP32.
// Round 8: prefetch DEPTH 2 (two named reg sets, manual 2x unroll) — R7's
// counters (Mfma 20%, VALU 27%, conflicts 0) showed a pure load-latency stall:
// 160cyc compute/K-step < 300-900cyc load latency. Depth-2 gives ~600cyc cover
// and counted-vmcnt for free. Everything else = R7 (128x128 tile, BK=64,
// 4 waves, T2 XOR swizzle, 1 barrier/iter dbuf LDS, XCD swizzle, fused a2a).

typedef _Float16 f16;
typedef _Float16 f16x2 __attribute__((ext_vector_type(2)));
typedef _Float16 f16x8 __attribute__((ext_vector_type(8)));
typedef float    f32x4 __attribute__((ext_vector_type(4)));

constexpr int Mdim = 28160;   // 8*44*80
constexpr int Ndim = 2048;
constexpr int Kdim = 2048;
constexpr int BM = 128, BN = 128, BK = 64;
constexpr int NWG = (Mdim / BM) * (Ndim / BN);  // 3520 (%8==0)
constexpr int NT  = Kdim / BK;                  // 32 (even -> clean 2x unroll)

struct RegSet { f32x4 a[8]; f32x4 b[8]; };

__device__ __forceinline__ f16x8 pack8(const f32x4& lo, const f32x4& hi) {
    f16x2 p0 = __builtin_bit_cast(f16x2, __builtin_amdgcn_cvt_pkrtz(lo[0], lo[1]));
    f16x2 p1 = __builtin_bit_cast(f16x2, __builtin_amdgcn_cvt_pkrtz(lo[2], lo[3]));
    f16x2 p2 = __builtin_bit_cast(f16x2, __builtin_amdgcn_cvt_pkrtz(hi[0], hi[1]));
    f16x2 p3 = __builtin_bit_cast(f16x2, __builtin_amdgcn_cvt_pkrtz(hi[2], hi[3]));
    return (f16x8){p0[0], p0[1], p1[0], p1[1], p2[0], p2[1], p3[0], p3[1]};
}

__global__ __launch_bounds__(256, 2)
void gemm_a2a_kernel(const float* __restrict__ X, const float* __restrict__ W,
                     float* __restrict__ out) {
    __shared__ f16 sA[2][BM * BK];   // 16 KiB each, swizzled layout
    __shared__ f16 sB[2][BN * BK];

    const int tid  = threadIdx.x;
    const int lane = tid & 63;
    const int wid  = tid >> 6;
    const int wr   = wid >> 1;
    const int wc   = wid & 1;

    const int cpx  = NWG >> 3;                       // XCD-bijective swizzle
    const int tile = (blockIdx.x & 7) * cpx + (blockIdx.x >> 3);
    const int bn   = tile & 15;
    const int bm   = tile >> 4;
    const int row0 = bm * BM;
    const int col0 = bn * BN;

    f32x4 acc[4][4] = {};
    RegSet rsA, rsB;   // depth-2 in-flight staging (named sets; rule #20)

    // chunk c8 = i*256+tid covers elements [c8*8 .. c8*8+7] of the 128x64 tile
    // (row = c8>>3, cols (c8&7)*8..+7); LDS byte = (c8*16) ^ ((row&7)<<4).
    auto load_tile = [&](int t, RegSet& rs) {
        const int k0 = t * BK;
#pragma unroll
        for (int i = 0; i < 4; ++i) {
            const int c8 = i * 256 + tid;
            const int r  = c8 >> 3;
            const int cc = (c8 & 7) * 8;
            const float* pa = X + (size_t)(row0 + r) * Kdim + k0 + cc;
            const float* pb = W + (size_t)(col0 + r) * Kdim + k0 + cc;
            rs.a[2*i]   = *(const f32x4*)pa;
            rs.a[2*i+1] = *(const f32x4*)(pa + 4);
            rs.b[2*i]   = *(const f32x4*)pb;
            rs.b[2*i+1] = *(const f32x4*)(pb + 4);
        }
    };
    auto write_tile = [&](int buf, RegSet& rs) {
#pragma unroll
        for (int i = 0; i < 4; ++i) {
            const int c8 = i * 256 + tid;
            const int sb = (c8 * 16) ^ (((c8 >> 3) & 7) << 4);
            *(f16x8*)((char*)sA[buf] + sb) = pack8(rs.a[2*i], rs.a[2*i+1]);
            *(f16x8*)((char*)sB[buf] + sb) = pack8(rs.b[2*i], rs.b[2*i+1]);
        }
    };
    auto compute_tile = [&](int buf) {
        const f16* Ab = sA[buf];
        const f16* Bb = sB[buf];
#pragma unroll
        for (int kk = 0; kk < BK; kk += 32) {
            const int kc = kk + (lane >> 4) * 8;   // frag row=lane&15, k=(lane>>4)*8+j
            f16x8 af[4], bfr[4];
#pragma unroll
            for (int f = 0; f < 4; ++f) {
                const int rowA = wr * 64 + f * 16 + (lane & 15);
                const int ba   = ((rowA * BK + kc) * 2) ^ ((rowA & 7) << 4);
                af[f] = *(const f16x8*)((const char*)Ab + ba);
                const int rowB = wc * 64 + f * 16 + (lane & 15);
                const int bb   = ((rowB * BK + kc) * 2) ^ ((rowB & 7) << 4);
                bfr[f] = *(const f16x8*)((const char*)Bb + bb);
            }
#pragma unroll
            for (int mi = 0; mi < 4; ++mi)
#pragma unroll
                for (int ni = 0; ni < 4; ++ni)
                    acc[mi][ni] = __builtin_amdgcn_mfma_f32_16x16x32_f16(
                        af[mi], bfr[ni], acc[mi][ni], 0, 0, 0);
        }
    };

    load_tile(0, rsA);      // in flight: setA(t=0)
    load_tile(1, rsB);      // in flight: setA(t=0), setB(t=1)
    int cur = 0;
    for (int t = 0; t < NT; t += 2) {
        // phase A: consume setA (issued 2 iters ago), refill with t+2
        write_tile(cur, rsA);                    // waits only setA (vmcnt(16))
        if (t + 2 < NT) load_tile(t + 2, rsA);
        __syncthreads();
        compute_tile(cur);
        cur ^= 1;
        // phase B: consume setB, refill with t+3
        write_tile(cur, rsB);
        if (t + 3 < NT) load_tile(t + 3, rsB);
        __syncthreads();
        compute_tile(cur);
        cur ^= 1;
    }

    // Epilogue: C/D col=lane&15 (n), row=(lane>>4)*4+j (m); fused all2all:
    // out[(n>>8)*M*256 + m*256 + (n&255)], f32 stores.
#pragma unroll
    for (int mi = 0; mi < 4; ++mi) {
#pragma unroll
        for (int ni = 0; ni < 4; ++ni) {
            const int n     = col0 + wc * 64 + ni * 16 + (lane & 15);
            const int rbase = row0 + wr * 64 + mi * 16 + (lane >> 4) * 4;
            const size_t obase = (size_t)(n >> 8) * ((size_t)Mdim * 256) + (n & 255);
#pragma unroll
            for (int j = 0; j < 4; ++j)
                out[obase + (size_t)(rbase + j) * 256] = acc[mi][ni][j];
        }
    }
}

extern "C" void kernel_launch(void* const* d_in, const int* in_sizes, int n_in,
                              void* d_out, int out_size, void* d_ws, size_t ws_size,
                              hipStream_t stream) {
    const float* X = (const float*)d_in[0];
    const float* W = (const float*)d_in[1];
    float* out     = (float*)d_out;
    hipLaunchKernelGGL(gemm_a2a_kernel, dim3(NWG), dim3(256), 0, stream, X, W, out);
}

// Round 9
// 446.408 us; speedup vs baseline: 2.7822x; 2.7822x over previous
//
#include <hip/hip_runtime.h>

// SPModel_6846177870356: y = x@W^T + all2all permute. M=28160, N=K=2048.
// Inputs FP32 (harness-upcast fp16), output FP32.
// Round 9: R8's spill disaster (WRITE 1.6GB scratch) -> drop reg staging
// entirely. Pre-convert X,W to f16 in d_ws with PRE-SWIZZLED global layout
// (Xs[m][k ^ ((m&7)<<3)] = X[m][k]); then m97-verified GEMM loop:
// global_load_lds width=16, linear src + linear LDS dest = swizzled LDS image
// (G21/m173), 2 barriers/K-step, conflict-free swizzled ds_read_b128,
// 32KB LDS, XCD-bijective swizzle, fused all2all f32 epilogue.

typedef _Float16 f16;
typedef _Float16 f16x2 __attribute__((ext_vector_type(2)));
typedef _Float16 f16x8 __attribute__((ext_vector_type(8)));
typedef float    f32x4 __attribute__((ext_vector_type(4)));

#define GPTR(p) ((const __attribute__((address_space(1))) void*)(p))
#define LPTR(p) ((__attribute__((address_space(3))) void*)(p))

constexpr int Mdim = 28160;   // 8*44*80
constexpr int Ndim = 2048;
constexpr int Kdim = 2048;
constexpr int BM = 128, BN = 128, BK = 64;
constexpr int NWG = (Mdim / BM) * (Ndim / BN);  // 3520 (%8==0)
constexpr size_t XS_ELEMS = (size_t)Mdim * Kdim;        // 57.7M
constexpr size_t WS_ELEMS = (size_t)Ndim * Kdim;        // 4.2M
constexpr size_t WS_NEED  = (XS_ELEMS + WS_ELEMS) * sizeof(f16);

__device__ __forceinline__ f16x8 pack8(const f32x4& lo, const f32x4& hi) {
    f16x2 p0 = __builtin_bit_cast(f16x2, __builtin_amdgcn_cvt_pkrtz(lo[0], lo[1]));
    f16x2 p1 = __builtin_bit_cast(f16x2, __builtin_amdgcn_cvt_pkrtz(lo[2], lo[3]));
    f16x2 p2 = __builtin_bit_cast(f16x2, __builtin_amdgcn_cvt_pkrtz(hi[0], hi[1]));
    f16x2 p3 = __builtin_bit_cast(f16x2, __builtin_amdgcn_cvt_pkrtz(hi[2], hi[3]));
    return (f16x8){p0[0], p0[1], p1[0], p1[1], p2[0], p2[1], p3[0], p3[1]};
}

// f32 [rows x 2048] -> f16 pre-swizzled: dst[m][k8 ^ (m&7)] (16B chunks).
__global__ __launch_bounds__(256)
void convert_kernel(const float* __restrict__ src, f16* __restrict__ dst) {
    const int idx = blockIdx.x * 256 + threadIdx.x;   // one 8-elem chunk
    const int m   = idx >> 8;                         // K/8 = 256 chunks/row
    const int k8  = idx & 255;
    const int k8s = k8 ^ (m & 7);                     // swizzle within K-step
    const float* p = src + (size_t)m * Kdim + k8 * 8;
    f32x4 lo = *(const f32x4*)p;
    f32x4 hi = *(const f32x4*)(p + 4);
    *(f16x8*)(dst + (size_t)m * Kdim + k8s * 8) = pack8(lo, hi);
}

__global__ __launch_bounds__(256)
void gemm_a2a_kernel(const f16* __restrict__ Xs, const f16* __restrict__ Ws,
                     float* __restrict__ out) {
    __shared__ f16 sA[BM * BK];   // 16 KiB, holds swizzled tile image
    __shared__ f16 sB[BN * BK];

    const int tid  = threadIdx.x;
    const int lane = tid & 63;
    const int wid  = tid >> 6;
    const int wr   = wid >> 1;
    const int wc   = wid & 1;

    const int cpx  = NWG >> 3;                       // XCD-bijective swizzle
    const int tile = (blockIdx.x & 7) * cpx + (blockIdx.x >> 3);
    const int bn   = tile & 15;
    const int bm   = tile >> 4;
    const int row0 = bm * BM;
    const int col0 = bn * BN;

    f32x4 acc[4][4] = {};

    for (int k0 = 0; k0 < Kdim; k0 += BK) {
        __syncthreads();   // prev compute done before LDS overwrite
        // Stage: linear src (pre-swizzled global) -> linear LDS = swizzled image.
#pragma unroll
        for (int i = 0; i < 4; ++i) {
            const int c8 = i * 256 + tid;     // 16B chunk index in 128x64 tile
            const int r  = c8 >> 3;
            const int cc = (c8 & 7) * 8;
            __builtin_amdgcn_global_load_lds(
                GPTR(Xs + (size_t)(row0 + r) * Kdim + k0 + cc),
                LPTR(&sA[c8 * 8]), 16, 0, 0);
            __builtin_amdgcn_global_load_lds(
                GPTR(Ws + (size_t)(col0 + r) * Kdim + k0 + cc),
                LPTR(&sB[c8 * 8]), 16, 0, 0);
        }
        __syncthreads();   // compiler drains vmcnt(0) before barrier (m97)

#pragma unroll
        for (int kk = 0; kk < BK; kk += 32) {
            const int kc = kk + (lane >> 4) * 8;   // frag row=lane&15, k=(lane>>4)*8+j
            f16x8 af[4], bfr[4];
#pragma unroll
            for (int f = 0; f < 4; ++f) {
                const int rowA = wr * 64 + f * 16 + (lane & 15);
                const int ba   = ((rowA * BK + kc) * 2) ^ ((rowA & 7) << 4);
                af[f] = *(const f16x8*)((const char*)sA + ba);
                const int rowB = wc * 64 + f * 16 + (lane & 15);
                const int bb   = ((rowB * BK + kc) * 2) ^ ((rowB & 7) << 4);
                bfr[f] = *(const f16x8*)((const char*)sB + bb);
            }
#pragma unroll
            for (int mi = 0; mi < 4; ++mi)
#pragma unroll
                for (int ni = 0; ni < 4; ++ni)
                    acc[mi][ni] = __builtin_amdgcn_mfma_f32_16x16x32_f16(
                        af[mi], bfr[ni], acc[mi][ni], 0, 0, 0);
        }
    }

    // Epilogue: C/D col=lane&15 (n), row=(lane>>4)*4+j (m); fused all2all:
    // out[(n>>8)*M*256 + m*256 + (n&255)], f32 stores.
#pragma unroll
    for (int mi = 0; mi < 4; ++mi) {
#pragma unroll
        for (int ni = 0; ni < 4; ++ni) {
            const int n     = col0 + wc * 64 + ni * 16 + (lane & 15);
            const int rbase = row0 + wr * 64 + mi * 16 + (lane >> 4) * 4;
            const size_t obase = (size_t)(n >> 8) * ((size_t)Mdim * 256) + (n & 255);
#pragma unroll
            for (int j = 0; j < 4; ++j)
                out[obase + (size_t)(rbase + j) * 256] = acc[mi][ni][j];
        }
    }
}

// ---- Fallback (R7-verified): direct-f32 reg-staged dbuf kernel ----
__global__ __launch_bounds__(256)
void gemm_a2a_f32_kernel(const float* __restrict__ X, const float* __restrict__ W,
                         float* __restrict__ out) {
    __shared__ f16 sA[2][BM * BK];
    __shared__ f16 sB[2][BN * BK];
    const int tid  = threadIdx.x;
    const int lane = tid & 63;
    const int wid  = tid >> 6;
    const int wr   = wid >> 1;
    const int wc   = wid & 1;
    const int cpx  = NWG >> 3;
    const int tile = (blockIdx.x & 7) * cpx + (blockIdx.x >> 3);
    const int bn   = tile & 15;
    const int bm   = tile >> 4;
    const int row0 = bm * BM;
    const int col0 = bn * BN;
    f32x4 acc[4][4] = {};
    f32x4 ra[8], rb[8];
    auto load_tile = [&](int t) {
#pragma unroll
        for (int i = 0; i < 4; ++i) {
            const int c8 = i * 256 + tid;
            const int r  = c8 >> 3;
            const int cc = (c8 & 7) * 8;
            const float* pa = X + (size_t)(row0 + r) * Kdim + t * BK + cc;
            const float* pb = W + (size_t)(col0 + r) * Kdim + t * BK + cc;
            ra[2*i] = *(const f32x4*)pa; ra[2*i+1] = *(const f32x4*)(pa + 4);
            rb[2*i] = *(const f32x4*)pb; rb[2*i+1] = *(const f32x4*)(pb + 4);
        }
    };
    int cur = 0;
    load_tile(0);
    for (int t = 0; t < Kdim / BK; ++t) {
#pragma unroll
        for (int i = 0; i < 4; ++i) {
            const int c8 = i * 256 + tid;
            const int sb = (c8 * 16) ^ (((c8 >> 3) & 7) << 4);
            *(f16x8*)((char*)sA[cur] + sb) = pack8(ra[2*i], ra[2*i+1]);
            *(f16x8*)((char*)sB[cur] + sb) = pack8(rb[2*i], rb[2*i+1]);
        }
        if (t + 1 < Kdim / BK) load_tile(t + 1);
        __syncthreads();
        const f16* Ab = sA[cur];
        const f16* Bb = sB[cur];
#pragma unroll
        for (int kk = 0; kk < BK; kk += 32) {
            const int kc = kk + (lane >> 4) * 8;
            f16x8 af[4], bfr[4];
#pragma unroll
            for (int f = 0; f < 4; ++f) {
                const int rowA = wr * 64 + f * 16 + (lane & 15);
                af[f] = *(const f16x8*)((const char*)Ab + (((rowA * BK + kc) * 2) ^ ((rowA & 7) << 4)));
                const int rowB = wc * 64 + f * 16 + (lane & 15);
                bfr[f] = *(const f16x8*)((const char*)Bb + (((rowB * BK + kc) * 2) ^ ((rowB & 7) << 4)));
            }
#pragma unroll
            for (int mi = 0; mi < 4; ++mi)
#pragma unroll
                for (int ni = 0; ni < 4; ++ni)
                    acc[mi][ni] = __builtin_amdgcn_mfma_f32_16x16x32_f16(
                        af[mi], bfr[ni], acc[mi][ni], 0, 0, 0);
        }
        cur ^= 1;
    }
#pragma unroll
    for (int mi = 0; mi < 4; ++mi)
#pragma unroll
        for (int ni = 0; ni < 4; ++ni) {
            const int n     = col0 + wc * 64 + ni * 16 + (lane & 15);
            const int rbase = row0 + wr * 64 + mi * 16 + (lane >> 4) * 4;
            const size_t obase = (size_t)(n >> 8) * ((size_t)Mdim * 256) + (n & 255);
#pragma unroll
            for (int j = 0; j < 4; ++j)
                out[obase + (size_t)(rbase + j) * 256] = acc[mi][ni][j];
        }
}

extern "C" void kernel_launch(void* const* d_in, const int* in_sizes, int n_in,
                              void* d_out, int out_size, void* d_ws, size_t ws_size,
                              hipStream_t stream) {
    const float* X = (const float*)d_in[0];
    const float* W = (const float*)d_in[1];
    float* out     = (float*)d_out;
    if (ws_size >= WS_NEED) {
        f16* Xs = (f16*)d_ws;
        f16* Ws = Xs + XS_ELEMS;
        hipLaunchKernelGGL(convert_kernel, dim3((int)(XS_ELEMS / 8 / 256)), dim3(256),
                           0, stream, X, Xs);
        hipLaunchKernelGGL(convert_kernel, dim3((int)(WS_ELEMS / 8 / 256)), dim3(256),
                           0, stream, W, Ws);
        hipLaunchKernelGGL(gemm_a2a_kernel, dim3(NWG), dim3(256), 0, stream, Xs, Ws, out);
    } else {
        hipLaunchKernelGGL(gemm_a2a_f32_kernel, dim3(NWG), dim3(256), 0, stream, X, W, out);
    }
}